// Round 2
// baseline (940.035 us; speedup 1.0000x reference)
//
#include <hip/hip_runtime.h>

// ============================================================================
// CNN3_P: fused conv front (pair+c1+c2+c3, per-sample, LDS ping-pong)
//         -> h3 (bf16, global) -> fc1 K-split GEMM -> reduce -> fc2
// Adaptive batch-chunking so ws usage fits ws_size (round-1 crash = suspected
// d_ws overflow at 544 MB).
// ============================================================================

typedef __attribute__((ext_vector_type(8))) short bf16x8;
typedef __attribute__((ext_vector_type(4))) float f32x4;
typedef __attribute__((ext_vector_type(8))) unsigned short u16x8;
typedef __attribute__((ext_vector_type(4))) unsigned short u16x4;

#define DEVINL __device__ __forceinline__

DEVINL unsigned short f2bf(float f) {
  unsigned u = __builtin_bit_cast(unsigned, f);
  return (unsigned short)((u + 0x7fffu + ((u >> 16) & 1u)) >> 16);  // RNE
}
DEVINL float bf2f(unsigned short h) {
  return __builtin_bit_cast(float, ((unsigned)h) << 16);
}
DEVINL f32x4 mfma16(bf16x8 a, bf16x8 b, f32x4 c) {
  return __builtin_amdgcn_mfma_f32_16x16x32_bf16(a, b, c, 0, 0, 0);
}
DEVINL float relu(float v) { return v > 0.f ? v : 0.f; }

constexpr int NB = 4096;

// ---------------------------------------------------------------- small weights
__global__ __launch_bounds__(256) void k_prep_w(
    const float* __restrict__ Wp, const float* __restrict__ W1,
    const float* __restrict__ W2, const float* __restrict__ W3,
    unsigned short* __restrict__ wp1r, unsigned short* __restrict__ w1r,
    unsigned short* __restrict__ w2r, unsigned short* __restrict__ w3r) {
  int idx = blockIdx.x * 256 + threadIdx.x;
  if (idx < 64 * 64) {  // Wp[:,:,1] -> [p][i]
    int p = idx >> 6, i = idx & 63;
    wp1r[idx] = f2bf(Wp[(p * 64 + i) * 2 + 1]);
    return;
  }
  idx -= 64 * 64;
  if (idx < 3 * 128 * 64) {  // W1 [o][c][k] -> [k][o][c]
    int k = idx / (128 * 64), r = idx % (128 * 64);
    int o = r >> 6, c = r & 63;
    w1r[idx] = f2bf(W1[(o * 64 + c) * 3 + k]);
    return;
  }
  idx -= 3 * 128 * 64;
  if (idx < 3 * 256 * 128) {
    int k = idx / (256 * 128), r = idx % (256 * 128);
    int o = r >> 7, c = r & 127;
    w2r[idx] = f2bf(W2[(o * 128 + c) * 3 + k]);
    return;
  }
  idx -= 3 * 256 * 128;
  if (idx < 3 * 256 * 256) {
    int k = idx >> 16, r = idx & 65535;
    int o = r >> 8, c = r & 255;
    w3r[idx] = f2bf(W3[(o * 256 + c) * 3 + k]);
  }
}

// ---------------------------------------------------------------- Wf1 remap (LDS transpose)
// dst col order: [0,30976): n=l*256+o <- src o*121+l ; [30976,39168): n=cl*64+il <- src il*128+cl
// one m-row per block; coalesced reads AND writes; padded LDS (<=2-way conflicts).
__global__ __launch_bounds__(256) void k_prep_wf1(const float* __restrict__ wf1,
                                                  unsigned short* __restrict__ wf1r) {
  extern __shared__ unsigned short tls[];  // 256*130 u16 = 66,560 B
  const int m = blockIdx.x, tid = threadIdx.x;
  const float* src = wf1 + (size_t)m * 39168;
  unsigned short* dst = wf1r + (size_t)m * 39168;
  for (int idx = tid; idx < 30976; idx += 256) {
    int o = idx / 121, l = idx - o * 121;
    tls[o * 130 + l] = f2bf(src[idx]);
  }
  __syncthreads();
  for (int idx = tid; idx < 30976; idx += 256) {
    int l = idx >> 8, o = idx & 255;
    dst[idx] = tls[o * 130 + l];
  }
  __syncthreads();
  for (int idx = tid; idx < 8192; idx += 256) {
    int il = idx >> 7, cl = idx & 127;
    tls[cl * 66 + il] = f2bf(src[30976 + idx]);
  }
  __syncthreads();
  for (int idx = tid; idx < 8192; idx += 256) {
    int cl = idx >> 6, il = idx & 63;
    dst[30976 + idx] = tls[cl * 66 + il];
  }
}

// ---------------------------------------------------------------- fused conv front
// One block per sample, 512 threads (8 waves). Dynamic LDS 98,992 B:
//   regA @u16[0]     : xs[128][72] -> h1s[125][136]   (34,048 B)
//   regB @u16[17024] : h0s[127][72] -> h2s[123][264]  (64,944 B)
// Row stride === 4 banks rotation mod 32 -> 2-way conflicts (free, m136).
__global__ __launch_bounds__(512) void k_front(
    const float* __restrict__ x, const float* __restrict__ Wp,
    const float* __restrict__ bp, const unsigned short* __restrict__ wp1r,
    const unsigned short* __restrict__ w1r, const float* __restrict__ b1,
    const unsigned short* __restrict__ w2r, const float* __restrict__ b2,
    const unsigned short* __restrict__ w3r, const float* __restrict__ b3,
    unsigned short* __restrict__ h3) {
  extern __shared__ unsigned short lds[];
  unsigned short* xs = lds;             // [128][72]
  unsigned short* h1s = lds;            // [125][136]
  unsigned short* h0s = lds + 17024;    // [127][72]
  unsigned short* h2s = lds + 17024;    // [123][264]
  __shared__ float pbase[8][64];
  __shared__ float basel[64];
  const int b = blockIdx.x, tid = threadIdx.x;
  const int lane = tid & 63, wv = tid >> 6, lq = lane >> 4, lr = lane & 15;
  const float* xb = x + (size_t)b * 8192;

  // phase 0: stage x -> xs bf16 [cl][il]
  for (int idx = tid * 4; idx < 8192; idx += 2048) {
    f32x4 v = *(const f32x4*)(xb + idx);
    int c = idx >> 6, i = idx & 63;
    u16x4 pk;
#pragma unroll
    for (int r = 0; r < 4; ++r) pk[r] = f2bf(v[r]);
    *(u16x4*)(xs + c * 72 + i) = pk;
  }
  __syncthreads();

  // phase 0b: base[p] = sum_i Wp[p][i][0]*x[b][i]
  {
    int p = tid & 63, q = tid >> 6;
    float s = 0.f;
#pragma unroll
    for (int t = 0; t < 8; ++t) {
      int i = q * 8 + t;
      s += Wp[(p * 64 + i) * 2] * bf2f(xs[i]);
    }
    pbase[q][p] = s;
  }
  __syncthreads();
  if (tid < 64) {
    float s = bp[tid];
#pragma unroll
    for (int q = 0; q < 8; ++q) s += pbase[q][tid];
    basel[tid] = s;
  }
  __syncthreads();

  // phase 1: pairwise GEMM (A=Wp1 64x64, B[i][j]=xs[j+1][i]) -> h0s[127][64]
  {
    const int mt = wv & 3, nh = wv >> 2;
    f32x4 acc[4];
#pragma unroll
    for (int t = 0; t < 4; ++t) acc[t] = (f32x4){0.f, 0.f, 0.f, 0.f};
#pragma unroll
    for (int s = 0; s < 2; ++s) {
      bf16x8 a = *(const bf16x8*)(wp1r + (mt * 16 + lr) * 64 + s * 32 + lq * 8);
#pragma unroll
      for (int t = 0; t < 4; ++t) {
        int j = (nh * 4 + t) * 16 + lr;
        int row = j + 1 > 127 ? 127 : j + 1;
        bf16x8 bb = *(const bf16x8*)(xs + row * 72 + s * 32 + lq * 8);
        acc[t] = mfma16(a, bb, acc[t]);
      }
    }
    const int m0 = mt * 16 + lq * 4;
    f32x4 bl;
#pragma unroll
    for (int r = 0; r < 4; ++r) bl[r] = basel[m0 + r];
#pragma unroll
    for (int t = 0; t < 4; ++t) {
      int j = (nh * 4 + t) * 16 + lr;
      if (j < 127) {
        u16x4 pk;
#pragma unroll
        for (int r = 0; r < 4; ++r) pk[r] = f2bf(relu(acc[t][r] + bl[r]));
        *(u16x4*)(h0s + j * 72 + m0) = pk;
      }
    }
  }
  __syncthreads();

  // phase 2: conv1 64->128, L 127->125: h0s -> h1s (overwrites xs region)
  {
    f32x4 acc[8];
#pragma unroll
    for (int nt = 0; nt < 8; ++nt) acc[nt] = (f32x4){0.f, 0.f, 0.f, 0.f};
#pragma unroll
    for (int k = 0; k < 3; ++k) {
      const unsigned short* wk = w1r + k * (128 * 64);
#pragma unroll
      for (int ks = 0; ks < 2; ++ks) {
        const int koff = ks * 32 + lq * 8;
        bf16x8 a = *(const bf16x8*)(wk + (wv * 16 + lr) * 64 + koff);
#pragma unroll
        for (int nt = 0; nt < 8; ++nt) {
          int l = nt * 16 + lr + k;
          if (l > 126) l = 126;
          bf16x8 bb = *(const bf16x8*)(h0s + l * 72 + koff);
          acc[nt] = mfma16(a, bb, acc[nt]);
        }
      }
    }
    const int m0 = wv * 16 + lq * 4;
    const f32x4 bi = *(const f32x4*)(b1 + m0);
#pragma unroll
    for (int nt = 0; nt < 8; ++nt) {
      int l = nt * 16 + lr;
      if (l < 125) {
        u16x4 pk;
#pragma unroll
        for (int r = 0; r < 4; ++r) pk[r] = f2bf(relu(acc[nt][r] + bi[r]));
        *(u16x4*)(h1s + l * 136 + m0) = pk;
      }
    }
  }
  __syncthreads();

  // phase 3: conv2 128->256, L 125->123: h1s -> h2s (overwrites h0s region)
  {
    f32x4 acc[2][8];
#pragma unroll
    for (int mi = 0; mi < 2; ++mi)
#pragma unroll
      for (int nt = 0; nt < 8; ++nt) acc[mi][nt] = (f32x4){0.f, 0.f, 0.f, 0.f};
#pragma unroll
    for (int k = 0; k < 3; ++k) {
      const unsigned short* wk = w2r + k * (256 * 128);
#pragma unroll
      for (int ks = 0; ks < 4; ++ks) {
        const int koff = ks * 32 + lq * 8;
        bf16x8 a0 = *(const bf16x8*)(wk + ((wv * 2 + 0) * 16 + lr) * 128 + koff);
        bf16x8 a1 = *(const bf16x8*)(wk + ((wv * 2 + 1) * 16 + lr) * 128 + koff);
#pragma unroll
        for (int nt = 0; nt < 8; ++nt) {
          int l = nt * 16 + lr + k;
          if (l > 124) l = 124;
          bf16x8 bb = *(const bf16x8*)(h1s + l * 136 + koff);
          acc[0][nt] = mfma16(a0, bb, acc[0][nt]);
          acc[1][nt] = mfma16(a1, bb, acc[1][nt]);
        }
      }
    }
#pragma unroll
    for (int mi = 0; mi < 2; ++mi) {
      const int m0 = (wv * 2 + mi) * 16 + lq * 4;
      const f32x4 bi = *(const f32x4*)(b2 + m0);
#pragma unroll
      for (int nt = 0; nt < 8; ++nt) {
        int l = nt * 16 + lr;
        if (l < 123) {
          u16x4 pk;
#pragma unroll
          for (int r = 0; r < 4; ++r) pk[r] = f2bf(relu(acc[mi][nt][r] + bi[r]));
          *(u16x4*)(h2s + l * 264 + m0) = pk;
        }
      }
    }
  }
  __syncthreads();

  // phase 4: conv3 256->256, L 123->121: h2s -> global h3 [b][l][o]
  {
    f32x4 acc[2][8];
#pragma unroll
    for (int mi = 0; mi < 2; ++mi)
#pragma unroll
      for (int nt = 0; nt < 8; ++nt) acc[mi][nt] = (f32x4){0.f, 0.f, 0.f, 0.f};
#pragma unroll
    for (int k = 0; k < 3; ++k) {
      const unsigned short* wk = w3r + k * 65536;
#pragma unroll
      for (int ks = 0; ks < 8; ++ks) {
        const int koff = ks * 32 + lq * 8;
        bf16x8 a0 = *(const bf16x8*)(wk + ((wv * 2 + 0) * 16 + lr) * 256 + koff);
        bf16x8 a1 = *(const bf16x8*)(wk + ((wv * 2 + 1) * 16 + lr) * 256 + koff);
#pragma unroll
        for (int nt = 0; nt < 8; ++nt) {
          int l = nt * 16 + lr + k;
          if (l > 122) l = 122;
          bf16x8 bb = *(const bf16x8*)(h2s + l * 264 + koff);
          acc[0][nt] = mfma16(a0, bb, acc[0][nt]);
          acc[1][nt] = mfma16(a1, bb, acc[1][nt]);
        }
      }
    }
#pragma unroll
    for (int mi = 0; mi < 2; ++mi) {
      const int m0 = (wv * 2 + mi) * 16 + lq * 4;
      const f32x4 bi = *(const f32x4*)(b3 + m0);
#pragma unroll
      for (int nt = 0; nt < 8; ++nt) {
        int l = nt * 16 + lr;
        if (l < 121) {
          u16x4 pk;
#pragma unroll
          for (int r = 0; r < 4; ++r) pk[r] = f2bf(relu(acc[mi][nt][r] + bi[r]));
          *(u16x4*)(h3 + ((size_t)b * 121 + l) * 256 + m0) = pk;
        }
      }
    }
  }
}

// ---------------------------------------------------------------- fc1 (K-split)
// feat[b] = h3[b] (30976, storage order l*256+o) ++ x[b] (8192, cl*64+il).
// wf1r columns pre-permuted to match. grid (chunkN/128, nslice).
__global__ __launch_bounds__(512) void k_fc1(const unsigned short* __restrict__ h3,
                                             const float* __restrict__ x,
                                             const unsigned short* __restrict__ wf1r,
                                             float* __restrict__ fpart,
                                             int chunkN, int cps) {
  __shared__ unsigned short lA[400 * 40];
  __shared__ unsigned short lB[128 * 40];
  const int tid = threadIdx.x;
  const int lane = tid & 63, wv = tid >> 6, lq = lane >> 4, lr = lane & 15;
  const int bbase = blockIdx.x * 128;
  const int slice = blockIdx.y;
  int c0 = slice * cps, c1 = c0 + cps;
  if (c1 > 1224) c1 = 1224;

  f32x4 acc[25];
#pragma unroll
  for (int mt = 0; mt < 25; ++mt) acc[mt] = (f32x4){0.f, 0.f, 0.f, 0.f};

  for (int kc = c0; kc < c1; ++kc) {
    const int k0 = kc * 32;
    for (int idx = tid; idx < 1600; idx += 512) {
      int mm = idx >> 2, ch = idx & 3;
      *(u16x8*)(lA + mm * 40 + ch * 8) =
          *(const u16x8*)(wf1r + (size_t)mm * 39168 + k0 + ch * 8);
    }
    {
      int n = tid >> 2, ch = tid & 3;
      int bb = bbase + n;
      u16x8 v;
      if (k0 < 30976) {  // 30976 % 32 == 0: chunk never straddles
        v = *(const u16x8*)(h3 + (size_t)bb * 30976 + k0 + ch * 8);
      } else {
        const float* sx = x + (size_t)bb * 8192 + (k0 - 30976) + ch * 8;
        f32x4 v0 = *(const f32x4*)sx;
        f32x4 v1 = *(const f32x4*)(sx + 4);
#pragma unroll
        for (int r = 0; r < 4; ++r) {
          v[r] = f2bf(v0[r]);
          v[4 + r] = f2bf(v1[r]);
        }
      }
      *(u16x8*)(lB + n * 40 + ch * 8) = v;
    }
    __syncthreads();
    bf16x8 bfr = *(const bf16x8*)(lB + (wv * 16 + lr) * 40 + lq * 8);
#pragma unroll
    for (int mt = 0; mt < 25; ++mt) {
      bf16x8 afr = *(const bf16x8*)(lA + (mt * 16 + lr) * 40 + lq * 8);
      acc[mt] = mfma16(afr, bfr, acc[mt]);
    }
    __syncthreads();
  }

  const int bb = bbase + wv * 16 + lr;
#pragma unroll
  for (int mt = 0; mt < 25; ++mt) {
    const int m0 = mt * 16 + lq * 4;
    *(f32x4*)(fpart + ((size_t)slice * chunkN + bb) * 400 + m0) = acc[mt];
  }
}

__global__ __launch_bounds__(256) void k_fc1red(const float* __restrict__ fpart,
                                                const float* __restrict__ bf1,
                                                float* __restrict__ fc,
                                                int chunkN, int nslice) {
  int idx = blockIdx.x * 256 + threadIdx.x;
  if (idx >= chunkN * 400) return;
  int m = idx % 400;
  float s = bf1[m];
  size_t stride = (size_t)chunkN * 400;
  for (int sl = 0; sl < nslice; ++sl) s += fpart[(size_t)sl * stride + idx];
  fc[idx] = relu(s);
}

__global__ __launch_bounds__(256) void k_fc2(const float* __restrict__ fc,
                                             const float* __restrict__ wf2,
                                             const float* __restrict__ bf2,
                                             float* __restrict__ out) {
  int b = blockIdx.x * 4 + (threadIdx.x >> 6);
  int lane = threadIdx.x & 63;
  float s = 0.f;
  for (int m = lane; m < 400; m += 64) s += fc[(size_t)b * 400 + m] * wf2[m];
#pragma unroll
  for (int off = 32; off > 0; off >>= 1) s += __shfl_down(s, off, 64);
  if (lane == 0) out[b] = s + bf2[0];
}

// ---------------------------------------------------------------- launch
extern "C" void kernel_launch(void* const* d_in, const int* in_sizes, int n_in,
                              void* d_out, int out_size, void* d_ws, size_t ws_size,
                              hipStream_t stream) {
  const float* x = (const float*)d_in[0];
  const float* Wp = (const float*)d_in[1];
  const float* bp = (const float*)d_in[2];
  const float* W1 = (const float*)d_in[3];
  const float* b1 = (const float*)d_in[4];
  const float* W2 = (const float*)d_in[5];
  const float* b2 = (const float*)d_in[6];
  const float* W3 = (const float*)d_in[7];
  const float* b3 = (const float*)d_in[8];
  const float* Wf1 = (const float*)d_in[9];
  const float* bf1 = (const float*)d_in[10];
  const float* Wf2 = (const float*)d_in[11];
  const float* bf2 = (const float*)d_in[12];
  float* out = (float*)d_out;

  // pick the largest chunking that fits ws_size
  static const int cand[6][2] = {{1, 8}, {2, 16}, {4, 32}, {8, 64}, {16, 64}, {32, 64}};
  const size_t fixed = 8192 + 49152 + 196608 + 393216 + 31334400ULL;  // small w + wf1r
  int nchunk = 32, nslice = 64;
  for (int i = 0; i < 6; ++i) {
    int nc = cand[i][0], ns = cand[i][1];
    size_t cn = NB / nc;
    size_t need = fixed + cn * 61952ULL + (size_t)ns * cn * 1600ULL + cn * 1600ULL;
    if (need <= ws_size) {
      nchunk = nc;
      nslice = ns;
      break;
    }
  }
  const int chunkN = NB / nchunk;
  const int cps = (1224 + nslice - 1) / nslice;  // 32-wide k-chunks per slice

  char* ws = (char*)d_ws;
  size_t off = 0;
  unsigned short* h3c = (unsigned short*)(ws + off);
  off += (size_t)chunkN * 61952ULL;
  float* fpart = (float*)(ws + off);
  off += (size_t)nslice * chunkN * 1600ULL;
  float* fc = (float*)(ws + off);
  off += (size_t)chunkN * 1600ULL;
  unsigned short* wp1r = (unsigned short*)(ws + off);
  off += 8192;
  unsigned short* w1r = (unsigned short*)(ws + off);
  off += 49152;
  unsigned short* w2r = (unsigned short*)(ws + off);
  off += 196608;
  unsigned short* w3r = (unsigned short*)(ws + off);
  off += 393216;
  unsigned short* wf1r = (unsigned short*)(ws + off);

  k_prep_w<<<1264, 256, 0, stream>>>(Wp, W1, W2, W3, wp1r, w1r, w2r, w3r);
  k_prep_wf1<<<400, 256, 66560, stream>>>(Wf1, wf1r);

  for (int c = 0; c < nchunk; ++c) {
    const float* xc = x + (size_t)c * chunkN * 8192;
    k_front<<<chunkN, 512, 98992, stream>>>(xc, Wp, bp, wp1r, w1r, b1, w2r, b2,
                                            w3r, b3, h3c);
    k_fc1<<<dim3(chunkN / 128, nslice), 512, 0, stream>>>(h3c, xc, wf1r, fpart,
                                                          chunkN, cps);
    k_fc1red<<<(chunkN * 400 + 255) / 256, 256, 0, stream>>>(fpart, bf1, fc,
                                                             chunkN, nslice);
    k_fc2<<<chunkN / 4, 256, 0, stream>>>(fc, Wf2, bf2, out + (size_t)c * chunkN);
  }
}

// Round 3
// 866.782 us; speedup vs baseline: 1.0845x; 1.0845x over previous
//
#include <hip/hip_runtime.h>

// ============================================================================
// CNN3_P r3: XOR-swizzled LDS in fused front (kills 8-way bank conflicts),
// fc1 rewritten: A-frags in registers from L2 (XCD-pinned wf1r slices),
// LDS used only for the batch-side B operand.
// ============================================================================

typedef __attribute__((ext_vector_type(8))) short bf16x8;
typedef __attribute__((ext_vector_type(4))) float f32x4;
typedef __attribute__((ext_vector_type(8))) unsigned short u16x8;
typedef __attribute__((ext_vector_type(4))) unsigned short u16x4;

#define DEVINL __device__ __forceinline__

DEVINL unsigned short f2bf(float f) {
  unsigned u = __builtin_bit_cast(unsigned, f);
  return (unsigned short)((u + 0x7fffu + ((u >> 16) & 1u)) >> 16);  // RNE
}
DEVINL float bf2f(unsigned short h) {
  return __builtin_bit_cast(float, ((unsigned)h) << 16);
}
DEVINL f32x4 mfma16(bf16x8 a, bf16x8 b, f32x4 c) {
  return __builtin_amdgcn_mfma_f32_16x16x32_bf16(a, b, c, 0, 0, 0);
}
DEVINL float relu(float v) { return v > 0.f ? v : 0.f; }

// XOR-swizzled u16 index: stride S (u16, pow2 >= 64), chunk ^= row&7 (T2 fix)
DEVINL int sx64(int r, int c) { return (r << 6) + ((((c >> 3) ^ (r & 7)) << 3)) + (c & 7); }
DEVINL int sx128(int r, int c) { return (r << 7) + ((((c >> 3) ^ (r & 7)) << 3)) + (c & 7); }
DEVINL int sx256(int r, int c) { return (r << 8) + ((((c >> 3) ^ (r & 7)) << 3)) + (c & 7); }

constexpr int NB = 4096;

// ---------------------------------------------------------------- small weights
__global__ __launch_bounds__(256) void k_prep_w(
    const float* __restrict__ Wp, const float* __restrict__ W1,
    const float* __restrict__ W2, const float* __restrict__ W3,
    unsigned short* __restrict__ wp1r, unsigned short* __restrict__ w1r,
    unsigned short* __restrict__ w2r, unsigned short* __restrict__ w3r) {
  int idx = blockIdx.x * 256 + threadIdx.x;
  if (idx < 64 * 64) {
    int p = idx >> 6, i = idx & 63;
    wp1r[idx] = f2bf(Wp[(p * 64 + i) * 2 + 1]);
    return;
  }
  idx -= 64 * 64;
  if (idx < 3 * 128 * 64) {
    int k = idx / (128 * 64), r = idx % (128 * 64);
    int o = r >> 6, c = r & 63;
    w1r[idx] = f2bf(W1[(o * 64 + c) * 3 + k]);
    return;
  }
  idx -= 3 * 128 * 64;
  if (idx < 3 * 256 * 128) {
    int k = idx / (256 * 128), r = idx % (256 * 128);
    int o = r >> 7, c = r & 127;
    w2r[idx] = f2bf(W2[(o * 128 + c) * 3 + k]);
    return;
  }
  idx -= 3 * 256 * 128;
  if (idx < 3 * 256 * 256) {
    int k = idx >> 16, r = idx & 65535;
    int o = r >> 8, c = r & 255;
    w3r[idx] = f2bf(W3[(o * 256 + c) * 3 + k]);
  }
}

// ---------------------------------------------------------------- Wf1 remap
__global__ __launch_bounds__(256) void k_prep_wf1(const float* __restrict__ wf1,
                                                  unsigned short* __restrict__ wf1r) {
  extern __shared__ unsigned short tls[];  // 256*130 u16
  const int m = blockIdx.x, tid = threadIdx.x;
  const float* src = wf1 + (size_t)m * 39168;
  unsigned short* dst = wf1r + (size_t)m * 39168;
  for (int idx = tid; idx < 30976; idx += 256) {
    int o = idx / 121, l = idx - o * 121;
    tls[o * 130 + l] = f2bf(src[idx]);
  }
  __syncthreads();
  for (int idx = tid; idx < 30976; idx += 256) {
    int l = idx >> 8, o = idx & 255;
    dst[idx] = tls[o * 130 + l];
  }
  __syncthreads();
  for (int idx = tid; idx < 8192; idx += 256) {
    int il = idx >> 7, cl = idx & 127;
    tls[cl * 66 + il] = f2bf(src[30976 + idx]);
  }
  __syncthreads();
  for (int idx = tid; idx < 8192; idx += 256) {
    int cl = idx >> 6, il = idx & 63;
    dst[30976 + idx] = tls[cl * 66 + il];
  }
}

// ---------------------------------------------------------------- fused conv front
// Regions (u16): A @0 : xs[128][64] -> h1s[125][128]  (16000 u16)
//                B @16000 : h0s[127][64] -> h2s[123][256] (31488 u16)
// All tiles XOR-swizzled (sx64/sx128/sx256). dyn LDS = 94,976 B.
__global__ __launch_bounds__(512) void k_front(
    const float* __restrict__ x, const float* __restrict__ Wp,
    const float* __restrict__ bp, const unsigned short* __restrict__ wp1r,
    const unsigned short* __restrict__ w1r, const float* __restrict__ b1,
    const unsigned short* __restrict__ w2r, const float* __restrict__ b2,
    const unsigned short* __restrict__ w3r, const float* __restrict__ b3,
    unsigned short* __restrict__ h3) {
  extern __shared__ unsigned short lds[];
  unsigned short* xs = lds;           // sx64
  unsigned short* h1s = lds;          // sx128
  unsigned short* h0s = lds + 16000;  // sx64
  unsigned short* h2s = lds + 16000;  // sx256
  __shared__ float pbase[8][64];
  __shared__ float basel[64];
  const int b = blockIdx.x, tid = threadIdx.x;
  const int lane = tid & 63, wv = tid >> 6, lq = lane >> 4, lr = lane & 15;
  const float* xb = x + (size_t)b * 8192;

  // phase 0: stage x -> xs bf16 [cl][il] (swizzled)
  for (int idx = tid * 4; idx < 8192; idx += 2048) {
    f32x4 v = *(const f32x4*)(xb + idx);
    int c = idx >> 6, i = idx & 63;
    u16x4 pk;
#pragma unroll
    for (int r = 0; r < 4; ++r) pk[r] = f2bf(v[r]);
    *(u16x4*)(xs + sx64(c, i)) = pk;
  }
  __syncthreads();

  // phase 0b: base[p] = sum_i Wp[p][i][0]*x[b][i]  (xs row 0 is unswizzled)
  {
    int p = tid & 63, q = tid >> 6;
    float s = 0.f;
#pragma unroll
    for (int t = 0; t < 8; ++t) {
      int i = q * 8 + t;
      s += Wp[(p * 64 + i) * 2] * bf2f(xs[i]);
    }
    pbase[q][p] = s;
  }
  __syncthreads();
  if (tid < 64) {
    float s = bp[tid];
#pragma unroll
    for (int q = 0; q < 8; ++q) s += pbase[q][tid];
    basel[tid] = s;
  }
  __syncthreads();

  // phase 1: pairwise GEMM -> h0s[127][64]
  {
    const int mt = wv & 3, nh = wv >> 2;
    f32x4 acc[4];
#pragma unroll
    for (int t = 0; t < 4; ++t) acc[t] = (f32x4){0.f, 0.f, 0.f, 0.f};
#pragma unroll
    for (int s = 0; s < 2; ++s) {
      bf16x8 a = *(const bf16x8*)(wp1r + (mt * 16 + lr) * 64 + s * 32 + lq * 8);
#pragma unroll
      for (int t = 0; t < 4; ++t) {
        int j = (nh * 4 + t) * 16 + lr;
        int row = j + 1 > 127 ? 127 : j + 1;
        bf16x8 bb = *(const bf16x8*)(xs + sx64(row, s * 32 + lq * 8));
        acc[t] = mfma16(a, bb, acc[t]);
      }
    }
    const int m0 = mt * 16 + lq * 4;
    f32x4 bl;
#pragma unroll
    for (int r = 0; r < 4; ++r) bl[r] = basel[m0 + r];
#pragma unroll
    for (int t = 0; t < 4; ++t) {
      int j = (nh * 4 + t) * 16 + lr;
      if (j < 127) {
        u16x4 pk;
#pragma unroll
        for (int r = 0; r < 4; ++r) pk[r] = f2bf(relu(acc[t][r] + bl[r]));
        *(u16x4*)(h0s + sx64(j, m0)) = pk;
      }
    }
  }
  __syncthreads();

  // phase 2: conv1 64->128, 127->125
  {
    f32x4 acc[8];
#pragma unroll
    for (int nt = 0; nt < 8; ++nt) acc[nt] = (f32x4){0.f, 0.f, 0.f, 0.f};
#pragma unroll
    for (int k = 0; k < 3; ++k) {
      const unsigned short* wk = w1r + k * (128 * 64);
#pragma unroll
      for (int ks = 0; ks < 2; ++ks) {
        const int koff = ks * 32 + lq * 8;
        bf16x8 a = *(const bf16x8*)(wk + (wv * 16 + lr) * 64 + koff);
#pragma unroll
        for (int nt = 0; nt < 8; ++nt) {
          int l = nt * 16 + lr + k;
          if (l > 126) l = 126;
          bf16x8 bb = *(const bf16x8*)(h0s + sx64(l, koff));
          acc[nt] = mfma16(a, bb, acc[nt]);
        }
      }
    }
    const int m0 = wv * 16 + lq * 4;
    const f32x4 bi = *(const f32x4*)(b1 + m0);
#pragma unroll
    for (int nt = 0; nt < 8; ++nt) {
      int l = nt * 16 + lr;
      if (l < 125) {
        u16x4 pk;
#pragma unroll
        for (int r = 0; r < 4; ++r) pk[r] = f2bf(relu(acc[nt][r] + bi[r]));
        *(u16x4*)(h1s + sx128(l, m0)) = pk;
      }
    }
  }
  __syncthreads();

  // phase 3: conv2 128->256, 125->123
  {
    f32x4 acc[2][8];
#pragma unroll
    for (int mi = 0; mi < 2; ++mi)
#pragma unroll
      for (int nt = 0; nt < 8; ++nt) acc[mi][nt] = (f32x4){0.f, 0.f, 0.f, 0.f};
#pragma unroll
    for (int k = 0; k < 3; ++k) {
      const unsigned short* wk = w2r + k * (256 * 128);
#pragma unroll
      for (int ks = 0; ks < 4; ++ks) {
        const int koff = ks * 32 + lq * 8;
        bf16x8 a0 = *(const bf16x8*)(wk + ((wv * 2 + 0) * 16 + lr) * 128 + koff);
        bf16x8 a1 = *(const bf16x8*)(wk + ((wv * 2 + 1) * 16 + lr) * 128 + koff);
#pragma unroll
        for (int nt = 0; nt < 8; ++nt) {
          int l = nt * 16 + lr + k;
          if (l > 124) l = 124;
          bf16x8 bb = *(const bf16x8*)(h1s + sx128(l, koff));
          acc[0][nt] = mfma16(a0, bb, acc[0][nt]);
          acc[1][nt] = mfma16(a1, bb, acc[1][nt]);
        }
      }
    }
#pragma unroll
    for (int mi = 0; mi < 2; ++mi) {
      const int m0 = (wv * 2 + mi) * 16 + lq * 4;
      const f32x4 bi = *(const f32x4*)(b2 + m0);
#pragma unroll
      for (int nt = 0; nt < 8; ++nt) {
        int l = nt * 16 + lr;
        if (l < 123) {
          u16x4 pk;
#pragma unroll
          for (int r = 0; r < 4; ++r) pk[r] = f2bf(relu(acc[mi][nt][r] + bi[r]));
          *(u16x4*)(h2s + sx256(l, m0)) = pk;
        }
      }
    }
  }
  __syncthreads();

  // phase 4: conv3 256->256, 123->121 -> global h3 [b][l][o]
  {
    f32x4 acc[2][8];
#pragma unroll
    for (int mi = 0; mi < 2; ++mi)
#pragma unroll
      for (int nt = 0; nt < 8; ++nt) acc[mi][nt] = (f32x4){0.f, 0.f, 0.f, 0.f};
#pragma unroll
    for (int k = 0; k < 3; ++k) {
      const unsigned short* wk = w3r + k * 65536;
#pragma unroll
      for (int ks = 0; ks < 8; ++ks) {
        const int koff = ks * 32 + lq * 8;
        bf16x8 a0 = *(const bf16x8*)(wk + ((wv * 2 + 0) * 16 + lr) * 256 + koff);
        bf16x8 a1 = *(const bf16x8*)(wk + ((wv * 2 + 1) * 16 + lr) * 256 + koff);
#pragma unroll
        for (int nt = 0; nt < 8; ++nt) {
          int l = nt * 16 + lr + k;
          if (l > 122) l = 122;
          bf16x8 bb = *(const bf16x8*)(h2s + sx256(l, koff));
          acc[0][nt] = mfma16(a0, bb, acc[0][nt]);
          acc[1][nt] = mfma16(a1, bb, acc[1][nt]);
        }
      }
    }
#pragma unroll
    for (int mi = 0; mi < 2; ++mi) {
      const int m0 = (wv * 2 + mi) * 16 + lq * 4;
      const f32x4 bi = *(const f32x4*)(b3 + m0);
#pragma unroll
      for (int nt = 0; nt < 8; ++nt) {
        int l = nt * 16 + lr;
        if (l < 121) {
          u16x4 pk;
#pragma unroll
          for (int r = 0; r < 4; ++r) pk[r] = f2bf(relu(acc[mi][nt][r] + bi[r]));
          *(u16x4*)(h3 + ((size_t)b * 121 + l) * 256 + m0) = pk;
        }
      }
    }
  }
}

// ---------------------------------------------------------------- fc1
// 1D grid (chunkN/128)*8: slice = bid&7 (XCD-pinned -> wf1r slice L2-resident),
// nb = bid>>3. Block: N=128 batch cols, M=400 (25 m-tiles), BK=64.
// A-frags in registers straight from global; lB [128][64] swizzled.
// wave wv owns m-tiles {3wv..3wv+2}; m-tile 24 split across waves by n-tile.
__global__ __launch_bounds__(512) void k_fc1(const unsigned short* __restrict__ h3,
                                             const float* __restrict__ x,
                                             const unsigned short* __restrict__ wf1r,
                                             float* __restrict__ fpart, int chunkN) {
  __shared__ unsigned short lB[128 * 64];
  const int tid = threadIdx.x;
  const int lane = tid & 63, wv = tid >> 6, lq = lane >> 4, lr = lane & 15;
  const int slice = blockIdx.x & 7;
  const int bbase = (blockIdx.x >> 3) * 128;
  const int c0 = slice * 76 + (slice < 4 ? slice : 4);
  const int c1 = c0 + 76 + (slice < 4 ? 1 : 0);

  f32x4 acc[3][8], acc24;
#pragma unroll
  for (int mi = 0; mi < 3; ++mi)
#pragma unroll
    for (int nt = 0; nt < 8; ++nt) acc[mi][nt] = (f32x4){0.f, 0.f, 0.f, 0.f};
  acc24 = (f32x4){0.f, 0.f, 0.f, 0.f};

  const size_t arow0 = (size_t)((3 * wv + 0) * 16 + lr) * 39168;
  const size_t arow1 = (size_t)((3 * wv + 1) * 16 + lr) * 39168;
  const size_t arow2 = (size_t)((3 * wv + 2) * 16 + lr) * 39168;
  const size_t arow24 = (size_t)(384 + lr) * 39168;

  for (int kc = c0; kc < c1; ++kc) {
    const int k0 = kc * 64;
    // stage B: 128 rows x 8 chunks, swizzled
#pragma unroll
    for (int t = 0; t < 2; ++t) {
      int idx = tid + t * 512;
      int n = idx >> 3, ch = idx & 7;
      int bb = bbase + n;
      u16x8 v;
      if (k0 < 30976) {
        v = *(const u16x8*)(h3 + (size_t)bb * 30976 + k0 + ch * 8);
      } else {
        const float* sxp = x + (size_t)bb * 8192 + (k0 - 30976) + ch * 8;
        f32x4 v0 = *(const f32x4*)sxp;
        f32x4 v1 = *(const f32x4*)(sxp + 4);
#pragma unroll
        for (int r = 0; r < 4; ++r) {
          v[r] = f2bf(v0[r]);
          v[4 + r] = f2bf(v1[r]);
        }
      }
      *(u16x8*)(lB + (n << 6) + ((ch ^ (n & 7)) << 3)) = v;
    }
    __syncthreads();

#pragma unroll
    for (int win = 0; win < 2; ++win) {
      const int koff = k0 + win * 32 + lq * 8;
      bf16x8 a0 = *(const bf16x8*)(wf1r + arow0 + koff);
      bf16x8 a1 = *(const bf16x8*)(wf1r + arow1 + koff);
      bf16x8 a2 = *(const bf16x8*)(wf1r + arow2 + koff);
      bf16x8 a24 = *(const bf16x8*)(wf1r + arow24 + koff);
      const int cloc = win * 32 + lq * 8;
#pragma unroll
      for (int nt = 0; nt < 8; ++nt) {
        const int n = nt * 16 + lr;
        bf16x8 bb = *(const bf16x8*)(lB + sx64(n, cloc));
        acc[0][nt] = mfma16(a0, bb, acc[0][nt]);
        acc[1][nt] = mfma16(a1, bb, acc[1][nt]);
        acc[2][nt] = mfma16(a2, bb, acc[2][nt]);
      }
      {
        const int n = wv * 16 + lr;
        bf16x8 bb = *(const bf16x8*)(lB + sx64(n, cloc));
        acc24 = mfma16(a24, bb, acc24);
      }
    }
    __syncthreads();
  }

  // write partials: fpart [slice][chunkN][400]
#pragma unroll
  for (int mi = 0; mi < 3; ++mi) {
    const int m0 = (3 * wv + mi) * 16 + lq * 4;
#pragma unroll
    for (int nt = 0; nt < 8; ++nt) {
      const int bb = bbase + nt * 16 + lr;
      *(f32x4*)(fpart + ((size_t)slice * chunkN + bb) * 400 + m0) = acc[mi][nt];
    }
  }
  {
    const int bb = bbase + wv * 16 + lr;
    *(f32x4*)(fpart + ((size_t)slice * chunkN + bb) * 400 + 384 + lq * 4) = acc24;
  }
}

__global__ __launch_bounds__(256) void k_fc1red(const float* __restrict__ fpart,
                                                const float* __restrict__ bf1,
                                                float* __restrict__ fc, int chunkN) {
  int idx = blockIdx.x * 256 + threadIdx.x;
  if (idx >= chunkN * 400) return;
  int m = idx % 400;
  float s = bf1[m];
  size_t stride = (size_t)chunkN * 400;
#pragma unroll
  for (int sl = 0; sl < 8; ++sl) s += fpart[(size_t)sl * stride + idx];
  fc[idx] = relu(s);
}

__global__ __launch_bounds__(256) void k_fc2(const float* __restrict__ fc,
                                             const float* __restrict__ wf2,
                                             const float* __restrict__ bf2,
                                             float* __restrict__ out) {
  int b = blockIdx.x * 4 + (threadIdx.x >> 6);
  int lane = threadIdx.x & 63;
  float s = 0.f;
  for (int m = lane; m < 400; m += 64) s += fc[(size_t)b * 400 + m] * wf2[m];
#pragma unroll
  for (int off = 32; off > 0; off >>= 1) s += __shfl_down(s, off, 64);
  if (lane == 0) out[b] = s + bf2[0];
}

// ---------------------------------------------------------------- launch
extern "C" void kernel_launch(void* const* d_in, const int* in_sizes, int n_in,
                              void* d_out, int out_size, void* d_ws, size_t ws_size,
                              hipStream_t stream) {
  const float* x = (const float*)d_in[0];
  const float* Wp = (const float*)d_in[1];
  const float* bp = (const float*)d_in[2];
  const float* W1 = (const float*)d_in[3];
  const float* b1 = (const float*)d_in[4];
  const float* W2 = (const float*)d_in[5];
  const float* b2 = (const float*)d_in[6];
  const float* W3 = (const float*)d_in[7];
  const float* b3 = (const float*)d_in[8];
  const float* Wf1 = (const float*)d_in[9];
  const float* bf1 = (const float*)d_in[10];
  const float* Wf2 = (const float*)d_in[11];
  const float* bf2 = (const float*)d_in[12];
  float* out = (float*)d_out;

  static const int cand[6] = {1, 2, 4, 8, 16, 32};
  const size_t fixed = 8192 + 49152 + 196608 + 393216 + 31334400ULL;
  int nchunk = 32;
  for (int i = 0; i < 6; ++i) {
    size_t cn = NB / cand[i];
    size_t need = fixed + cn * 61952ULL + 8 * cn * 1600ULL + cn * 1600ULL;
    if (need <= ws_size) {
      nchunk = cand[i];
      break;
    }
  }
  const int chunkN = NB / nchunk;

  char* ws = (char*)d_ws;
  size_t off = 0;
  unsigned short* h3c = (unsigned short*)(ws + off);
  off += (size_t)chunkN * 61952ULL;
  float* fpart = (float*)(ws + off);
  off += 8ULL * chunkN * 1600ULL;
  float* fc = (float*)(ws + off);
  off += (size_t)chunkN * 1600ULL;
  unsigned short* wp1r = (unsigned short*)(ws + off);
  off += 8192;
  unsigned short* w1r = (unsigned short*)(ws + off);
  off += 49152;
  unsigned short* w2r = (unsigned short*)(ws + off);
  off += 196608;
  unsigned short* w3r = (unsigned short*)(ws + off);
  off += 393216;
  unsigned short* wf1r = (unsigned short*)(ws + off);

  k_prep_w<<<1264, 256, 0, stream>>>(Wp, W1, W2, W3, wp1r, w1r, w2r, w3r);
  k_prep_wf1<<<400, 256, 66560, stream>>>(Wf1, wf1r);

  for (int c = 0; c < nchunk; ++c) {
    const float* xc = x + (size_t)c * chunkN * 8192;
    k_front<<<chunkN, 512, 94976, stream>>>(xc, Wp, bp, wp1r, w1r, b1, w2r, b2,
                                            w3r, b3, h3c);
    k_fc1<<<(chunkN / 128) * 8, 512, 0, stream>>>(h3c, xc, wf1r, fpart, chunkN);
    k_fc1red<<<(chunkN * 400 + 255) / 256, 256, 0, stream>>>(fpart, bf1, fc, chunkN);
    k_fc2<<<chunkN / 4, 256, 0, stream>>>(fc, Wf2, bf2, out + (size_t)c * chunkN);
  }
}

// Round 4
// 770.563 us; speedup vs baseline: 1.2199x; 1.1249x over previous
//
#include <hip/hip_runtime.h>

// ============================================================================
// CNN3_P r4: conv phases re-tiled 4mt x 4nt per wave (B-frag feeds 4 MFMA ->
// LDS ops halved), conv weights pre-packed per-MFMA-fragment (coalesced 1024B
// global A-loads from L2). nchunk=4 so h3/fpart stay LLC-resident; fc1 32
// K-slices, XCD-pinned.
// ============================================================================

typedef __attribute__((ext_vector_type(8))) short bf16x8;
typedef __attribute__((ext_vector_type(4))) float f32x4;
typedef __attribute__((ext_vector_type(8))) unsigned short u16x8;
typedef __attribute__((ext_vector_type(4))) unsigned short u16x4;

#define DEVINL __device__ __forceinline__

DEVINL unsigned short f2bf(float f) {
  unsigned u = __builtin_bit_cast(unsigned, f);
  return (unsigned short)((u + 0x7fffu + ((u >> 16) & 1u)) >> 16);  // RNE
}
DEVINL float bf2f(unsigned short h) {
  return __builtin_bit_cast(float, ((unsigned)h) << 16);
}
DEVINL f32x4 mfma16(bf16x8 a, bf16x8 b, f32x4 c) {
  return __builtin_amdgcn_mfma_f32_16x16x32_bf16(a, b, c, 0, 0, 0);
}
DEVINL float relu(float v) { return v > 0.f ? v : 0.f; }
// swizzled LDS index (u16 units): row r, col c, row-stride 2^sh u16
DEVINL int sxg(int r, int c, int sh) {
  return (r << sh) + (((c >> 3) ^ (r & 7)) << 3) + (c & 7);
}

constexpr int NB = 4096;

// ---------------------------------------------------------------- prep weights
// wp1r: [p][i] 64x64. w1p/w2p/w3p: per-fragment packed:
// frag f = (k*KS+ks)*MT+mt; elem: lane l, e: o=mt*16+(l&15), c=ks*32+(l>>4)*8+e
__global__ __launch_bounds__(256) void k_prep_w(
    const float* __restrict__ Wp, const float* __restrict__ W1,
    const float* __restrict__ W2, const float* __restrict__ W3,
    unsigned short* __restrict__ wp1r, unsigned short* __restrict__ w1p,
    unsigned short* __restrict__ w2p, unsigned short* __restrict__ w3p) {
  int idx = blockIdx.x * 256 + threadIdx.x;
  if (idx < 4096) {
    int p = idx >> 6, i = idx & 63;
    wp1r[idx] = f2bf(Wp[(p * 64 + i) * 2 + 1]);
    return;
  }
  idx -= 4096;
  if (idx < 24576) {  // w1: KS=2, MT=8 -> 48 frags
    int f = idx >> 9, l = (idx >> 3) & 63, e = idx & 7;
    int mt = f & 7, t = f >> 3, ks = t & 1, k = t >> 1;
    int o = mt * 16 + (l & 15), c = ks * 32 + (l >> 4) * 8 + e;
    w1p[idx] = f2bf(W1[(o * 64 + c) * 3 + k]);
    return;
  }
  idx -= 24576;
  if (idx < 98304) {  // w2: KS=4, MT=16 -> 192 frags
    int f = idx >> 9, l = (idx >> 3) & 63, e = idx & 7;
    int mt = f & 15, t = f >> 4, ks = t & 3, k = t >> 2;
    int o = mt * 16 + (l & 15), c = ks * 32 + (l >> 4) * 8 + e;
    w2p[idx] = f2bf(W2[(o * 128 + c) * 3 + k]);
    return;
  }
  idx -= 98304;
  if (idx < 196608) {  // w3: KS=8, MT=16 -> 384 frags
    int f = idx >> 9, l = (idx >> 3) & 63, e = idx & 7;
    int mt = f & 15, t = f >> 4, ks = t & 7, k = t >> 3;
    int o = mt * 16 + (l & 15), c = ks * 32 + (l >> 4) * 8 + e;
    w3p[idx] = f2bf(W3[(o * 256 + c) * 3 + k]);
  }
}

// ---------------------------------------------------------------- Wf1 remap
__global__ __launch_bounds__(256) void k_prep_wf1(const float* __restrict__ wf1,
                                                  unsigned short* __restrict__ wf1r) {
  extern __shared__ unsigned short tls[];  // 256*130 u16
  const int m = blockIdx.x, tid = threadIdx.x;
  const float* src = wf1 + (size_t)m * 39168;
  unsigned short* dst = wf1r + (size_t)m * 39168;
  for (int idx = tid; idx < 30976; idx += 256) {
    int o = idx / 121, l = idx - o * 121;
    tls[o * 130 + l] = f2bf(src[idx]);
  }
  __syncthreads();
  for (int idx = tid; idx < 30976; idx += 256) {
    int l = idx >> 8, o = idx & 255;
    dst[idx] = tls[o * 130 + l];
  }
  __syncthreads();
  for (int idx = tid; idx < 8192; idx += 256) {
    int il = idx >> 7, cl = idx & 127;
    tls[cl * 66 + il] = f2bf(src[30976 + idx]);
  }
  __syncthreads();
  for (int idx = tid; idx < 8192; idx += 256) {
    int cl = idx >> 6, il = idx & 63;
    dst[30976 + idx] = tls[cl * 66 + il];
  }
}

// ---------------------------------------------------------------- conv phase
// wave-grid 4m x 2n; wave = MPW m-tiles x 4 n-tiles. A coalesced from packed
// global (1024B/frag), B from swizzled LDS (each read feeds MPW MFMAs).
template <int CIN, int COUT, int LIN, int LOUT, int SSHI, int SSHO, bool TOGLB>
DEVINL void conv16(const unsigned short* in_lds,
                   const unsigned short* __restrict__ wpack,
                   const float* __restrict__ bias, unsigned short* out_lds,
                   unsigned short* h3, int b, int lane, int wv) {
  constexpr int KS = CIN / 32;
  constexpr int MT = COUT / 16;
  constexpr int MPW = MT / 4;
  const int lr = lane & 15, lq = lane >> 4;
  const int wm = wv >> 1, wn = wv & 1;
  f32x4 acc[MPW][4];
#pragma unroll
  for (int mi = 0; mi < MPW; ++mi)
#pragma unroll
    for (int ni = 0; ni < 4; ++ni) acc[mi][ni] = (f32x4){0.f, 0.f, 0.f, 0.f};
#pragma unroll
  for (int k = 0; k < 3; ++k)
#pragma unroll
    for (int ks = 0; ks < KS; ++ks) {
      bf16x8 a[MPW];
#pragma unroll
      for (int mi = 0; mi < MPW; ++mi)
        a[mi] = *(const bf16x8*)(wpack +
                                 (((k * KS + ks) * MT + wm * MPW + mi) << 9) +
                                 lane * 8);
      const int col = ks * 32 + lq * 8;
#pragma unroll
      for (int ni = 0; ni < 4; ++ni) {
        int l = (wn * 4 + ni) * 16 + lr + k;
        if (l > LIN - 1) l = LIN - 1;  // garbage cols >= LOUT, never stored
        bf16x8 bb = *(const bf16x8*)(in_lds + sxg(l, col, SSHI));
#pragma unroll
        for (int mi = 0; mi < MPW; ++mi) acc[mi][ni] = mfma16(a[mi], bb, acc[mi][ni]);
      }
    }
#pragma unroll
  for (int mi = 0; mi < MPW; ++mi) {
    const int o0 = (wm * MPW + mi) * 16 + lq * 4;
    const f32x4 bi = *(const f32x4*)(bias + o0);
#pragma unroll
    for (int ni = 0; ni < 4; ++ni) {
      const int l = (wn * 4 + ni) * 16 + lr;
      if (l < LOUT) {
        u16x4 pk;
#pragma unroll
        for (int r = 0; r < 4; ++r) pk[r] = f2bf(relu(acc[mi][ni][r] + bi[r]));
        if constexpr (TOGLB)
          *(u16x4*)(h3 + ((size_t)b * LOUT + l) * COUT + o0) = pk;
        else
          *(u16x4*)(out_lds + sxg(l, o0, SSHO)) = pk;
      }
    }
  }
}

// ---------------------------------------------------------------- fused front
// Regions (u16): A @0     : xs[128]<<6 -> h1s[125]<<7   (16000)
//                B @16000 : h0s[127]<<6 -> h2s[123]<<8  (31488)
// dyn LDS = 94,976 B.
__global__ __launch_bounds__(512) void k_front(
    const float* __restrict__ x, const float* __restrict__ Wp,
    const float* __restrict__ bp, const unsigned short* __restrict__ wp1r,
    const unsigned short* __restrict__ w1p, const float* __restrict__ b1,
    const unsigned short* __restrict__ w2p, const float* __restrict__ b2,
    const unsigned short* __restrict__ w3p, const float* __restrict__ b3,
    unsigned short* __restrict__ h3) {
  extern __shared__ unsigned short lds[];
  unsigned short* xs = lds;
  unsigned short* h1s = lds;
  unsigned short* h0s = lds + 16000;
  unsigned short* h2s = lds + 16000;
  __shared__ float pbase[8][64];
  __shared__ float basel[64];
  const int b = blockIdx.x, tid = threadIdx.x;
  const int lane = tid & 63, wv = tid >> 6, lq = lane >> 4, lr = lane & 15;
  const float* xb = x + (size_t)b * 8192;

  // phase 0: stage x -> xs bf16 [cl][il] swizzled
  for (int idx = tid * 4; idx < 8192; idx += 2048) {
    f32x4 v = *(const f32x4*)(xb + idx);
    int c = idx >> 6, i = idx & 63;
    u16x4 pk;
#pragma unroll
    for (int r = 0; r < 4; ++r) pk[r] = f2bf(v[r]);
    *(u16x4*)(xs + sxg(c, i, 6)) = pk;
  }
  __syncthreads();

  // phase 0b: base[p] = sum_i Wp[p][i][0]*x[b][i]   (xs row 0 unswizzled)
  {
    int p = tid & 63, q = tid >> 6;
    float s = 0.f;
#pragma unroll
    for (int t = 0; t < 8; ++t) {
      int i = q * 8 + t;
      s += Wp[(p * 64 + i) * 2] * bf2f(xs[i]);
    }
    pbase[q][p] = s;
  }
  __syncthreads();
  if (tid < 64) {
    float s = bp[tid];
#pragma unroll
    for (int q = 0; q < 8; ++q) s += pbase[q][tid];
    basel[tid] = s;
  }
  __syncthreads();

  // phase 1: pairwise GEMM (A=Wp1 64x64, B[i][j]=xs[j+1][i]) -> h0s[127][64]
  {
    const int mt = wv & 3, nh = wv >> 2;
    f32x4 acc[4];
#pragma unroll
    for (int t = 0; t < 4; ++t) acc[t] = (f32x4){0.f, 0.f, 0.f, 0.f};
#pragma unroll
    for (int s = 0; s < 2; ++s) {
      bf16x8 a = *(const bf16x8*)(wp1r + (mt * 16 + lr) * 64 + s * 32 + lq * 8);
#pragma unroll
      for (int t = 0; t < 4; ++t) {
        int j = (nh * 4 + t) * 16 + lr;
        int row = j + 1 > 127 ? 127 : j + 1;
        bf16x8 bb = *(const bf16x8*)(xs + sxg(row, s * 32 + lq * 8, 6));
        acc[t] = mfma16(a, bb, acc[t]);
      }
    }
    const int m0 = mt * 16 + lq * 4;
    f32x4 bl;
#pragma unroll
    for (int r = 0; r < 4; ++r) bl[r] = basel[m0 + r];
#pragma unroll
    for (int t = 0; t < 4; ++t) {
      int j = (nh * 4 + t) * 16 + lr;
      if (j < 127) {
        u16x4 pk;
#pragma unroll
        for (int r = 0; r < 4; ++r) pk[r] = f2bf(relu(acc[t][r] + bl[r]));
        *(u16x4*)(h0s + sxg(j, m0, 6)) = pk;
      }
    }
  }
  __syncthreads();

  // phase 2: conv1 64->128, 127->125
  conv16<64, 128, 127, 125, 6, 7, false>(h0s, w1p, b1, h1s, nullptr, b, lane, wv);
  __syncthreads();
  // phase 3: conv2 128->256, 125->123
  conv16<128, 256, 125, 123, 7, 8, false>(h1s, w2p, b2, h2s, nullptr, b, lane, wv);
  __syncthreads();
  // phase 4: conv3 256->256, 123->121 -> global h3 [b][l][o]
  conv16<256, 256, 123, 121, 8, 0, true>(h2s, w3p, b3, nullptr, h3, b, lane, wv);
}

// ---------------------------------------------------------------- fc1
// grid (chunkN/128)*32, slice = bid&31 (slice%8 = XCD -> 4 slices/XCD, wf1r
// slice set ~3.9MB L2-resident). A-frags in regs from global; lB swizzled.
__global__ __launch_bounds__(512) void k_fc1(const unsigned short* __restrict__ h3,
                                             const float* __restrict__ x,
                                             const unsigned short* __restrict__ wf1r,
                                             float* __restrict__ fpart, int chunkN) {
  __shared__ unsigned short lB[128 * 64];
  const int tid = threadIdx.x;
  const int lane = tid & 63, wv = tid >> 6, lq = lane >> 4, lr = lane & 15;
  const int slice = blockIdx.x & 31;
  const int bbase = (blockIdx.x >> 5) * 128;
  const int c0 = slice * 19 + (slice < 4 ? slice : 4);
  const int c1 = c0 + 19 + (slice < 4 ? 1 : 0);

  f32x4 acc[3][8], acc24;
#pragma unroll
  for (int mi = 0; mi < 3; ++mi)
#pragma unroll
    for (int nt = 0; nt < 8; ++nt) acc[mi][nt] = (f32x4){0.f, 0.f, 0.f, 0.f};
  acc24 = (f32x4){0.f, 0.f, 0.f, 0.f};

  const size_t arow0 = (size_t)((3 * wv + 0) * 16 + lr) * 39168;
  const size_t arow1 = (size_t)((3 * wv + 1) * 16 + lr) * 39168;
  const size_t arow2 = (size_t)((3 * wv + 2) * 16 + lr) * 39168;
  const size_t arow24 = (size_t)(384 + lr) * 39168;

  for (int kc = c0; kc < c1; ++kc) {
    const int k0 = kc * 64;
#pragma unroll
    for (int t = 0; t < 2; ++t) {
      int idx = tid + t * 512;
      int n = idx >> 3, ch = idx & 7;
      int bb = bbase + n;
      u16x8 v;
      if (k0 < 30976) {  // 30976 % 64 == 0: never straddles
        v = *(const u16x8*)(h3 + (size_t)bb * 30976 + k0 + ch * 8);
      } else {
        const float* sxp = x + (size_t)bb * 8192 + (k0 - 30976) + ch * 8;
        f32x4 v0 = *(const f32x4*)sxp;
        f32x4 v1 = *(const f32x4*)(sxp + 4);
#pragma unroll
        for (int r = 0; r < 4; ++r) {
          v[r] = f2bf(v0[r]);
          v[4 + r] = f2bf(v1[r]);
        }
      }
      *(u16x8*)(lB + (n << 6) + ((ch ^ (n & 7)) << 3)) = v;
    }
    __syncthreads();

#pragma unroll
    for (int win = 0; win < 2; ++win) {
      const int koff = k0 + win * 32 + lq * 8;
      bf16x8 a0 = *(const bf16x8*)(wf1r + arow0 + koff);
      bf16x8 a1 = *(const bf16x8*)(wf1r + arow1 + koff);
      bf16x8 a2 = *(const bf16x8*)(wf1r + arow2 + koff);
      bf16x8 a24 = *(const bf16x8*)(wf1r + arow24 + koff);
      const int cloc = win * 32 + lq * 8;
#pragma unroll
      for (int nt = 0; nt < 8; ++nt) {
        const int n = nt * 16 + lr;
        bf16x8 bb = *(const bf16x8*)(lB + sxg(n, cloc, 6));
        acc[0][nt] = mfma16(a0, bb, acc[0][nt]);
        acc[1][nt] = mfma16(a1, bb, acc[1][nt]);
        acc[2][nt] = mfma16(a2, bb, acc[2][nt]);
      }
      {
        const int n = wv * 16 + lr;
        bf16x8 bb = *(const bf16x8*)(lB + sxg(n, cloc, 6));
        acc24 = mfma16(a24, bb, acc24);
      }
    }
    __syncthreads();
  }

#pragma unroll
  for (int mi = 0; mi < 3; ++mi) {
    const int m0 = (3 * wv + mi) * 16 + lq * 4;
#pragma unroll
    for (int nt = 0; nt < 8; ++nt) {
      const int bb = bbase + nt * 16 + lr;
      *(f32x4*)(fpart + ((size_t)slice * chunkN + bb) * 400 + m0) = acc[mi][nt];
    }
  }
  {
    const int bb = bbase + wv * 16 + lr;
    *(f32x4*)(fpart + ((size_t)slice * chunkN + bb) * 400 + 384 + lq * 4) = acc24;
  }
}

__global__ __launch_bounds__(256) void k_fc1red(const float* __restrict__ fpart,
                                                const float* __restrict__ bf1,
                                                float* __restrict__ fc, int chunkN) {
  int idx = blockIdx.x * 256 + threadIdx.x;
  if (idx >= chunkN * 400) return;
  int m = idx % 400;
  float s = bf1[m];
  size_t stride = (size_t)chunkN * 400;
#pragma unroll 8
  for (int sl = 0; sl < 32; ++sl) s += fpart[(size_t)sl * stride + idx];
  fc[idx] = relu(s);
}

__global__ __launch_bounds__(256) void k_fc2(const float* __restrict__ fc,
                                             const float* __restrict__ wf2,
                                             const float* __restrict__ bf2,
                                             float* __restrict__ out) {
  int b = blockIdx.x * 4 + (threadIdx.x >> 6);
  int lane = threadIdx.x & 63;
  float s = 0.f;
  for (int m = lane; m < 400; m += 64) s += fc[(size_t)b * 400 + m] * wf2[m];
#pragma unroll
  for (int off = 32; off > 0; off >>= 1) s += __shfl_down(s, off, 64);
  if (lane == 0) out[b] = s + bf2[0];
}

// ---------------------------------------------------------------- launch
extern "C" void kernel_launch(void* const* d_in, const int* in_sizes, int n_in,
                              void* d_out, int out_size, void* d_ws, size_t ws_size,
                              hipStream_t stream) {
  const float* x = (const float*)d_in[0];
  const float* Wp = (const float*)d_in[1];
  const float* bp = (const float*)d_in[2];
  const float* W1 = (const float*)d_in[3];
  const float* b1 = (const float*)d_in[4];
  const float* W2 = (const float*)d_in[5];
  const float* b2 = (const float*)d_in[6];
  const float* W3 = (const float*)d_in[7];
  const float* b3 = (const float*)d_in[8];
  const float* Wf1 = (const float*)d_in[9];
  const float* bf1 = (const float*)d_in[10];
  const float* Wf2 = (const float*)d_in[11];
  const float* bf2 = (const float*)d_in[12];
  float* out = (float*)d_out;

  // nchunk=4 keeps h3 chunk + fpart LLC-resident; fall back if ws too small
  static const int cand[4] = {4, 8, 16, 32};
  const size_t fixed = 8192 + 49152 + 196608 + 393216 + 31334400ULL;
  int nchunk = 32;
  for (int i = 0; i < 4; ++i) {
    size_t cn = NB / cand[i];
    size_t need = fixed + cn * 61952ULL + 32ULL * cn * 1600ULL + cn * 1600ULL;
    if (need <= ws_size) {
      nchunk = cand[i];
      break;
    }
  }
  const int chunkN = NB / nchunk;

  char* ws = (char*)d_ws;
  size_t off = 0;
  unsigned short* h3c = (unsigned short*)(ws + off);
  off += (size_t)chunkN * 61952ULL;
  float* fpart = (float*)(ws + off);
  off += 32ULL * chunkN * 1600ULL;
  float* fc = (float*)(ws + off);
  off += (size_t)chunkN * 1600ULL;
  unsigned short* wp1r = (unsigned short*)(ws + off);
  off += 8192;
  unsigned short* w1p = (unsigned short*)(ws + off);
  off += 49152;
  unsigned short* w2p = (unsigned short*)(ws + off);
  off += 196608;
  unsigned short* w3p = (unsigned short*)(ws + off);
  off += 393216;
  unsigned short* wf1r = (unsigned short*)(ws + off);

  k_prep_w<<<1264, 256, 0, stream>>>(Wp, W1, W2, W3, wp1r, w1p, w2p, w3p);
  k_prep_wf1<<<400, 256, 66560, stream>>>(Wf1, wf1r);

  for (int c = 0; c < nchunk; ++c) {
    const float* xc = x + (size_t)c * chunkN * 8192;
    k_front<<<chunkN, 512, 94976, stream>>>(xc, Wp, bp, wp1r, w1p, b1, w2p, b2,
                                            w3p, b3, h3c);
    k_fc1<<<(chunkN / 128) * 32, 512, 0, stream>>>(h3c, xc, wf1r, fpart, chunkN);
    k_fc1red<<<(chunkN * 400 + 255) / 256, 256, 0, stream>>>(fpart, bf1, fc, chunkN);
    k_fc2<<<chunkN / 4, 256, 0, stream>>>(fc, Wf2, bf2, out + (size_t)c * chunkN);
  }
}